// Round 1
// 153.341 us; speedup vs baseline: 2.8509x; 2.8509x over previous
//
#include <hip/hip_runtime.h>
#include <hip/hip_bf16.h>

// AGREE fused, round 8: latency-bound fix. Previous round: 30KB LDS capped
// occupancy at ~5 waves/CU (13.9%), serial lane-0 softmax + 26 barriers +
// per-block weight staging dominated (VALUBusy 15%, HBM 1.9%).
// This round: lane=member attention (no intra-MLP barriers, uniform scalar
// weight loads via K$ instead of LDS staging), wave-parallel softmax via
// shuffles, shuffle-tree prediction reduce, ballot-prefix gather of only the
// valid members (avg 25.5/50), 4-rows-per-iteration vectorized gather.
// LDS 30720B -> ~13.3KB => 12 blocks/CU. Only 2 __syncthreads total.
// Probe kernel (mask width + f32/bf16 layout) unchanged from the verified
// round-6/7 version; style kept to the known-compiling subset.

__global__ void AGREE_12773232738622_probe(
    const void* member_mask,            // [8192, 50] unknown element width
    const void* user_table,             // [100000, 64] f32 or bf16
    int* ws)                            // ws[0] = mask width (1/2/4/8), ws[1] = isf32
{
    __shared__ int s_val[4][64];
    __shared__ int s_len[4][64];
    const int lane = threadIdx.x;       // 64 lanes, lane = sample row
    const unsigned char* mb = (const unsigned char*)member_mask;

    for (int wi = 0; wi < 4; ++wi) {
        int W = 1 << wi;
        int len = 0, ok = 1, prev = 1;
        for (int m = 0; m < 50; ++m) {
            long off = (long)W * (50L * lane + m);
            int nz = 0;
            for (int t = 0; t < W; ++t) nz = nz | (mb[off + t] != 0);
            if (nz && !prev) ok = 0;    // a gap -> not a prefix -> wrong width
            if (nz) len = len + 1;
            prev = nz;
        }
        if (len == 0) ok = 0;
        s_val[wi][lane] = ok;
        s_len[wi][lane] = len;
    }
    __syncthreads();

    if (lane == 0) {
        int bestW = 1, bestLen = -1;
        for (int wi = 0; wi < 4; ++wi) {
            int allok = 1, mx = 0;
            for (int r = 0; r < 64; ++r) {
                if (!s_val[wi][r]) allok = 0;
                if (s_len[wi][r] > mx) mx = s_len[wi][r];
            }
            if (allok && mx > bestLen) { bestLen = mx; bestW = (1 << wi); }
        }
        ws[0] = bestW;

        int huge = 0;
        for (int i = 0; i < 64; ++i) {
            float v = __bfloat162float(((const __hip_bfloat16*)user_table)[i]);
            float a = (v < 0.0f) ? -v : v;
            if (!(a < 4.0f)) huge = huge + 1;   // catches NaN too
        }
        ws[1] = (huge >= 8) ? 1 : 0;
    }
}

__global__ void AGREE_12773232738622_kernel(
    const int* member_idx,              // [8192, 50] int32
    const void* member_mask,            // [8192, 50] width in ws[0]
    const int* item_inputs,             // [8192] int32
    const void* user_table,             // [100000, 64]
    const void* item_table,             // [50000, 64]
    const void* att_w1,                 // [128, 16]
    const void* att_b1,                 // [16]
    const void* att_w2,                 // [16, 1]
    const void* att_b2,                 // [1]
    const void* pred_w1,                // [192, 8]
    const void* pred_b1,                // [8]
    const void* pred_w2,                // [8, 1]
    const void* pred_b2,                // [1]
    void* out,                          // [8192] (dtype follows ws[1])
    const int* ws)
{
    __shared__ float s_mem[50][65];     // member embeddings f32; pad 65 keeps both
                                        // access patterns <=2-way bank aliased (free)
    __shared__ float s_wt[50];          // softmax weights
    __shared__ float s_hit[16];         // item half of attention layer 1 (+b1)

    const int b    = blockIdx.x;
    const int lane = threadIdx.x;
    const int mode = ws[0];
    const int isf  = ws[1];

    // ---- mask: one element per lane, prefix length via ballot (uniform) ----
    int valid = 0;
    if (lane < 50) {
        long e0 = 50L * b + lane;
        if (mode == 1)      valid = (((const unsigned char*)member_mask)[e0] != 0);
        else if (mode == 2) valid = (((const unsigned short*)member_mask)[e0] != 0);
        else if (mode == 4) valid = (((const unsigned int*)member_mask)[e0] != 0u);
        else {
            const unsigned int* p = (const unsigned int*)member_mask;
            valid = ((p[2 * e0] | p[2 * e0 + 1]) != 0u);
        }
    }
    unsigned long long vm = __ballot(valid);
    int len = __popcll(vm);
    if (len < 1)  len = 1;              // unreachable if probe is right
    if (len > 50) len = 50;

    // ---- item embedding, lane = dim ----
    const int item_id = item_inputs[b];
    float itemv;
    if (isf) itemv = ((const float*)item_table)[item_id * 64 + lane];
    else     itemv = __bfloat162float(((const __hip_bfloat16*)item_table)[item_id * 64 + lane]);

    // ---- gather valid member rows: 4 rows/iter, 16B (f32) or 8B (bf16) per lane ----
    int idxv = 0;
    if (lane < 50) idxv = member_idx[b * 50 + lane];
    const int gr = lane >> 4;           // row-in-quad 0..3
    const int gc = lane & 15;           // chunk 0..15
    const int nIter = (len + 3) >> 2;
    if (isf) {
        const float* ut = (const float*)user_table;
        for (int i = 0; i < nIter; ++i) {
            int m = i * 4 + gr;
            int id = __shfl(idxv, (m < 50) ? m : 0);
            if (m < len) {
                float4 v = ((const float4*)(ut + (long)id * 64))[gc];
                s_mem[m][gc * 4 + 0] = v.x;
                s_mem[m][gc * 4 + 1] = v.y;
                s_mem[m][gc * 4 + 2] = v.z;
                s_mem[m][gc * 4 + 3] = v.w;
            }
        }
    } else {
        const unsigned short* ut = (const unsigned short*)user_table;
        for (int i = 0; i < nIter; ++i) {
            int m = i * 4 + gr;
            int id = __shfl(idxv, (m < 50) ? m : 0);
            if (m < len) {
                ushort4 v = ((const ushort4*)(ut + (long)id * 64))[gc];
                s_mem[m][gc * 4 + 0] = __uint_as_float((unsigned int)v.x << 16);
                s_mem[m][gc * 4 + 1] = __uint_as_float((unsigned int)v.y << 16);
                s_mem[m][gc * 4 + 2] = __uint_as_float((unsigned int)v.z << 16);
                s_mem[m][gc * 4 + 3] = __uint_as_float((unsigned int)v.w << 16);
            }
        }
    }

    // ---- item half of att layer 1 (+b1), via register shuffles on itemv ----
    {
        const int k = lane & 15;
        const int c = lane >> 4;        // 4 chunks of 16 features
        float part;
        if (isf) part = (c == 0) ? ((const float*)att_b1)[k] : 0.0f;
        else     part = (c == 0) ? __bfloat162float(((const __hip_bfloat16*)att_b1)[k]) : 0.0f;
        for (int t = 0; t < 16; ++t) {
            int f = c * 16 + t;
            float iv = __shfl(itemv, f);
            float w;
            if (isf) w = ((const float*)att_w1)[(64 + f) * 16 + k];
            else     w = __bfloat162float(((const __hip_bfloat16*)att_w1)[(64 + f) * 16 + k]);
            part += iv * w;
        }
        part += __shfl_xor(part, 16);
        part += __shfl_xor(part, 32);
        if (lane < 16) s_hit[lane] = part;
    }
    __syncthreads();                    // barrier 1: s_mem + s_hit ready

    // ---- attention MLP, lane = member; weights are wave-uniform (scalar loads) ----
    const int mm = (lane < len) ? lane : (len - 1);
    float h[16];
    #pragma unroll
    for (int k = 0; k < 16; ++k) h[k] = s_hit[k];
    if (isf) {
        const float* w1 = (const float*)att_w1;
        #pragma unroll 8
        for (int f = 0; f < 64; ++f) {
            float mv = s_mem[mm][f];
            #pragma unroll
            for (int k = 0; k < 16; ++k) h[k] += mv * w1[f * 16 + k];
        }
    } else {
        const __hip_bfloat16* w1 = (const __hip_bfloat16*)att_w1;
        #pragma unroll 8
        for (int f = 0; f < 64; ++f) {
            float mv = s_mem[mm][f];
            #pragma unroll
            for (int k = 0; k < 16; ++k) h[k] += mv * __bfloat162float(w1[f * 16 + k]);
        }
    }
    float lg;
    if (isf) lg = ((const float*)att_b2)[0];
    else     lg = __bfloat162float(((const __hip_bfloat16*)att_b2)[0]);
    #pragma unroll
    for (int k = 0; k < 16; ++k) {
        float hk = fmaxf(h[k], 0.0f);
        float w2;
        if (isf) w2 = ((const float*)att_w2)[k];
        else     w2 = __bfloat162float(((const __hip_bfloat16*)att_w2)[k]);
        lg += hk * w2;
    }

    // ---- masked softmax, fully wave-parallel ----
    float x = valid ? lg : -3.0e38f;
    float mx = x;
    mx = fmaxf(mx, __shfl_xor(mx, 1));
    mx = fmaxf(mx, __shfl_xor(mx, 2));
    mx = fmaxf(mx, __shfl_xor(mx, 4));
    mx = fmaxf(mx, __shfl_xor(mx, 8));
    mx = fmaxf(mx, __shfl_xor(mx, 16));
    mx = fmaxf(mx, __shfl_xor(mx, 32));
    float p = valid ? expf(x - mx) : 0.0f;
    float sum = p;
    sum += __shfl_xor(sum, 1);
    sum += __shfl_xor(sum, 2);
    sum += __shfl_xor(sum, 4);
    sum += __shfl_xor(sum, 8);
    sum += __shfl_xor(sum, 16);
    sum += __shfl_xor(sum, 32);
    float wnorm;
    if (sum > 0.0f) wnorm = p * (1.0f / sum);
    else            wnorm = (lane == 0) ? 1.0f : 0.0f;   // structural NaN guard
    if (lane < 50) s_wt[lane] = wnorm;
    __syncthreads();                    // barrier 2: weights ready

    // ---- weighted pooling, lane = dim (only valid members touched) ----
    float g = 0.0f;
    for (int m = 0; m < len; ++m) g += s_wt[m] * s_mem[m][lane];

    // ---- prediction MLP: new = [g*item, g, item], reduce via shuffles ----
    const float gi = g * itemv;
    float p8[8];
    if (isf) {
        const float* pw = (const float*)pred_w1;
        #pragma unroll
        for (int k2 = 0; k2 < 8; ++k2) {
            p8[k2] = gi    * pw[lane * 8 + k2]
                   + g     * pw[(64 + lane) * 8 + k2]
                   + itemv * pw[(128 + lane) * 8 + k2];
        }
    } else {
        const __hip_bfloat16* pw = (const __hip_bfloat16*)pred_w1;
        #pragma unroll
        for (int k2 = 0; k2 < 8; ++k2) {
            p8[k2] = gi    * __bfloat162float(pw[lane * 8 + k2])
                   + g     * __bfloat162float(pw[(64 + lane) * 8 + k2])
                   + itemv * __bfloat162float(pw[(128 + lane) * 8 + k2]);
        }
    }
    #pragma unroll
    for (int k2 = 0; k2 < 8; ++k2) {
        float v = p8[k2];
        v += __shfl_xor(v, 1);
        v += __shfl_xor(v, 2);
        v += __shfl_xor(v, 4);
        v += __shfl_xor(v, 8);
        v += __shfl_xor(v, 16);
        v += __shfl_xor(v, 32);
        p8[k2] = v;
    }
    if (lane == 0) {
        float z;
        if (isf) z = ((const float*)pred_b2)[0];
        else     z = __bfloat162float(((const __hip_bfloat16*)pred_b2)[0]);
        for (int k2 = 0; k2 < 8; ++k2) {
            float bb, ww;
            if (isf) {
                bb = ((const float*)pred_b1)[k2];
                ww = ((const float*)pred_w2)[k2];
            } else {
                bb = __bfloat162float(((const __hip_bfloat16*)pred_b1)[k2]);
                ww = __bfloat162float(((const __hip_bfloat16*)pred_w2)[k2]);
            }
            float hh = p8[k2] + bb;
            if (hh < 0.0f) hh = 0.0f;
            z += hh * ww;
        }
        float y = 1.0f / (1.0f + expf(-z));
        if (isf) ((float*)out)[b] = y;
        else     ((__hip_bfloat16*)out)[b] = __float2bfloat16(y);
    }
}

extern "C" void kernel_launch(void* const* d_in, const int* in_sizes, int n_in,
                              void* d_out, int out_size, void* d_ws, size_t ws_size,
                              hipStream_t stream) {
    (void)in_sizes; (void)n_in; (void)out_size; (void)ws_size;
    AGREE_12773232738622_probe<<<1, 64, 0, stream>>>(
        d_in[1], d_in[3], (int*)d_ws);
    AGREE_12773232738622_kernel<<<8192, 64, 0, stream>>>(
        (const int*)d_in[0],
        d_in[1],
        (const int*)d_in[2],
        d_in[3],
        d_in[4],
        d_in[5],
        d_in[6],
        d_in[7],
        d_in[8],
        d_in[9],
        d_in[10],
        d_in[11],
        d_in[12],
        d_out,
        (const int*)d_ws);
}